// Round 12
// baseline (69.200 us; speedup 1.0000x reference)
//
#include <hip/hip_runtime.h>

// DetectionLayer (YOLO head decode), fp32.
// x:   (B=32, C=255, G=76, G=76)  where C = a*85 + k, k in [0,85)
// out: (B, 3*76*76, 85)
// Per (b,a): transpose 85 x 5776 -> 5776 x 85 with per-k elementwise math.
//   k=0: (sigmoid(v)+gx)*stride      k=1: (sigmoid(v)+gy)*stride
//   k=2: exp(v)*anchors[a].w         k=3: exp(v)*anchors[a].h   (stride cancels)
//   k>=4: sigmoid(v)
//
// R11 = R10 (XCD swizzle, 62.6us) + multi-tile blocks: 2184 blocks x 4
// consecutive logical tiles each. Wave-private LDS, no barriers; tile t+1
// global loads overlap tile t NT stores (no dependency) -> load pipe stays
// fed across tile boundaries instead of draining at block teardown.
// R9 lesson: no manual load hoisting (compiler schedules MLP fine).

#define GDIM   76
#define GG     5776      // 76*76
#define NC     85        // 80 classes + 5
#define NA     3
#define NCH    255       // NA*NC
#define NCELLS 17328     // NA*GG
#define STRIDEF 8.0f     // 608/76
#define TC     64        // cells per block-tile (4 waves x 16)
#define NTILE  91        // per plane: 90 full + 1 edge tile (16 cells)
#define NT_LOG (32 * NA * NTILE)   // 8736 logical tiles
#define TPB    4                   // tiles per block
#define NBLK   (NT_LOG / TPB)      // 2184 blocks, % 8 == 0
#define CPX    (NBLK / 8)          // 273 blocks per XCD

typedef float f32x4 __attribute__((ext_vector_type(4)));

__device__ __forceinline__ float sigf(float v) {
    return 1.0f / (1.0f + __expf(-v));
}

__device__ __forceinline__ float decode(float val, int k, int s, float aw, float ah) {
    if (k == 0)      return (sigf(val) + (float)(s % GDIM)) * STRIDEF;
    else if (k == 1) return (sigf(val) + (float)(s / GDIM)) * STRIDEF;
    else if (k == 2) return __expf(val) * aw;
    else if (k == 3) return __expf(val) * ah;
    else             return sigf(val);
}

__global__ __launch_bounds__(256)
void det_decode_kernel(const float* __restrict__ x,
                       const float* __restrict__ anchors,
                       float* __restrict__ out) {
    __shared__ float lds[4][16 * NC];   // per-wave private [cell][k]

    const int wave = threadIdx.x >> 6;
    const int lane = threadIdx.x & 63;

    // XCD-aware bijective swizzle on blocks; each block owns TPB consecutive
    // logical tiles -> per-XCD contiguous tile ranges (L2 locality).
    const int hw   = blockIdx.x;
    const int blk  = (hw & 7) * CPX + (hw >> 3);

    float* __restrict__ ldsw = lds[wave];

    #pragma unroll
    for (int tt = 0; tt < TPB; ++tt) {
        const int t    = blk * TPB + tt;       // logical tile id
        const int tile = t % NTILE;
        const int ba   = t / NTILE;
        const int a    = ba % NA;
        const int b    = ba / NA;

        const int s0   = tile * TC;
        const bool full = (GG - s0 >= TC);     // tile 90 is the 16-cell edge

        const float aw = anchors[2 * a];
        const float ah = anchors[2 * a + 1];

        if (full) {
            const int ws0 = s0 + wave * 16;    // this wave's 16 cells
            const float* __restrict__ srcw = x + (size_t)(b * NCH + a * NC) * GG + ws0;
            float* __restrict__ dstw = out + (size_t)(b * NCELLS + a * GG + ws0) * NC;

            // Phase 1: 85 k-rows x 4 quads = 340 float4 loads; per instr the
            // wave covers 16 k-rows x 64B aligned. Scatter to lds[cell][k].
            #pragma unroll
            for (int it = 0; it < 6; ++it) {
                const int e = lane + 64 * it;
                if (e < NC * 4) {
                    const int k    = e >> 2;
                    const int cell = (e & 3) * 4;
                    const f32x4 v = *reinterpret_cast<const f32x4*>(srcw + (size_t)k * GG + cell);
                    #pragma unroll
                    for (int j = 0; j < 4; ++j)
                        ldsw[(cell + j) * NC + k] = decode(v[j], k, ws0 + cell + j, aw, ah);
                }
            }

            // Phase 2: wave's output span = 16*85 = 1360 contiguous floats,
            // same linear order as LDS. Same-wave dependency only, no barrier.
            #pragma unroll
            for (int it = 0; it < 6; ++it) {
                const int e = lane + 64 * it;
                if (e < 340) {
                    const f32x4 v = *reinterpret_cast<const f32x4*>(ldsw + 4 * e);
                    __builtin_nontemporal_store(v, reinterpret_cast<f32x4*>(dstw + 4 * e));
                }
            }
        } else {
            const int ws0 = s0 + wave * 4;     // edge: 4 cells per wave
            const float* __restrict__ srcw = x + (size_t)(b * NCH + a * NC) * GG + ws0;
            float* __restrict__ dstw = out + (size_t)(b * NCELLS + a * GG + ws0) * NC;

            #pragma unroll
            for (int it = 0; it < 2; ++it) {
                const int k = lane + 64 * it;  // one quad per k-row
                if (k < NC) {
                    const f32x4 v = *reinterpret_cast<const f32x4*>(srcw + (size_t)k * GG);
                    #pragma unroll
                    for (int j = 0; j < 4; ++j)
                        ldsw[j * NC + k] = decode(v[j], k, ws0 + j, aw, ah);
                }
            }
            #pragma unroll
            for (int it = 0; it < 2; ++it) {
                const int e = lane + 64 * it;  // 4*85 = 340 floats = 85 float4
                if (e < NC) {
                    const f32x4 v = *reinterpret_cast<const f32x4*>(ldsw + 4 * e);
                    __builtin_nontemporal_store(v, reinterpret_cast<f32x4*>(dstw + 4 * e));
                }
            }
        }
    }
}

extern "C" void kernel_launch(void* const* d_in, const int* in_sizes, int n_in,
                              void* d_out, int out_size, void* d_ws, size_t ws_size,
                              hipStream_t stream) {
    const float* x       = (const float*)d_in[0];
    const float* anchors = (const float*)d_in[1];
    float* out           = (float*)d_out;

    det_decode_kernel<<<dim3(NBLK), dim3(256), 0, stream>>>(x, anchors, out);
}

// Round 13
// 62.168 us; speedup vs baseline: 1.1131x; 1.1131x over previous
//
#include <hip/hip_runtime.h>

// DetectionLayer (YOLO head decode), fp32.
// x:   (B=32, C=255, G=76, G=76)  where C = a*85 + k, k in [0,85)
// out: (B, 3*76*76, 85)
// Per (b,a): transpose 85 x 5776 -> 5776 x 85 with per-k elementwise math.
//   k=0: (sigmoid(v)+gx)*stride      k=1: (sigmoid(v)+gy)*stride
//   k=2: exp(v)*anchors[a].w         k=3: exp(v)*anchors[a].h   (stride cancels)
//   k>=4: sigmoid(v)
//
// FINAL = R10 (best: 62.56us, 6.03 TB/s fabric = 96% of copy ceiling).
// - wave-private 16-cell sub-tiles, no __syncthreads (R4)
// - XCD-aware bijective block swizzle: each XCD owns 1092 consecutive
//   logical tiles = exactly 12 complete (b,a) planes (R10: fetch -20%)
// - NT float4 stores; [cell][85] LDS = linear output order
// Refuted: barrier removal (R6 neutral), 12-cell tiles (R7 worse fetch),
// manual MLP hoisting (R9 regressed), multi-tile blocks (R12 regressed).

#define GDIM   76
#define GG     5776      // 76*76
#define NC     85        // 80 classes + 5
#define NA     3
#define NCH    255       // NA*NC
#define NCELLS 17328     // NA*GG
#define STRIDEF 8.0f     // 608/76
#define TC     64        // cells per block-tile (4 waves x 16)
#define NTILE  91        // 90 full + 1 edge tile of 16 cells (4 waves x 4)
#define NBLK   (32 * NA * NTILE)   // 8736
#define CPX    (NBLK / 8)          // 1092 blocks per XCD

typedef float f32x4 __attribute__((ext_vector_type(4)));

__device__ __forceinline__ float sigf(float v) {
    return 1.0f / (1.0f + __expf(-v));
}

__device__ __forceinline__ float decode(float val, int k, int s, float aw, float ah) {
    if (k == 0)      return (sigf(val) + (float)(s % GDIM)) * STRIDEF;
    else if (k == 1) return (sigf(val) + (float)(s / GDIM)) * STRIDEF;
    else if (k == 2) return __expf(val) * aw;
    else if (k == 3) return __expf(val) * ah;
    else             return sigf(val);
}

__global__ __launch_bounds__(256)
void det_decode_kernel(const float* __restrict__ x,
                       const float* __restrict__ anchors,
                       float* __restrict__ out) {
    __shared__ float lds[4][16 * NC];   // per-wave private [cell][k]

    const int wave = threadIdx.x >> 6;
    const int lane = threadIdx.x & 63;

    // XCD-aware bijective swizzle: hw blockIdx round-robins XCDs (hw%8);
    // give XCD x the contiguous logical range [x*CPX, (x+1)*CPX).
    const int hw   = blockIdx.x;
    const int blk  = (hw & 7) * CPX + (hw >> 3);

    const int tile = blk % NTILE;
    const int ba   = blk / NTILE;
    const int a    = ba % NA;
    const int b    = ba / NA;

    const int s0   = tile * TC;
    const bool full = (GG - s0 >= TC);          // 90 full tiles, 1 edge (16 cells)

    const float aw = anchors[2 * a];
    const float ah = anchors[2 * a + 1];

    float* __restrict__ ldsw = lds[wave];

    if (full) {
        const int ws0 = s0 + wave * 16;         // this wave's 16 cells
        const float* __restrict__ srcw = x + (size_t)(b * NCH + a * NC) * GG + ws0;
        float* __restrict__ dstw = out + (size_t)(b * NCELLS + a * GG + ws0) * NC;

        // Phase 1: 85 k-rows x 4 quads = 340 float4 loads; per instr the wave
        // covers 16 k-rows x 64B aligned. Scatter to lds[cell][k].
        #pragma unroll
        for (int it = 0; it < 6; ++it) {
            const int e = lane + 64 * it;
            if (e < NC * 4) {
                const int k    = e >> 2;
                const int cell = (e & 3) * 4;
                const f32x4 v = *reinterpret_cast<const f32x4*>(srcw + (size_t)k * GG + cell);
                #pragma unroll
                for (int j = 0; j < 4; ++j)
                    ldsw[(cell + j) * NC + k] = decode(v[j], k, ws0 + cell + j, aw, ah);
            }
        }

        // Phase 2: wave's output span = 16*85 = 1360 contiguous floats, same
        // linear order as LDS. No barrier needed (same-wave dependency).
        #pragma unroll
        for (int it = 0; it < 6; ++it) {
            const int e = lane + 64 * it;
            if (e < 340) {
                const f32x4 v = *reinterpret_cast<const f32x4*>(ldsw + 4 * e);
                __builtin_nontemporal_store(v, reinterpret_cast<f32x4*>(dstw + 4 * e));
            }
        }
    } else {
        const int ws0 = s0 + wave * 4;          // edge: 4 cells per wave
        const float* __restrict__ srcw = x + (size_t)(b * NCH + a * NC) * GG + ws0;
        float* __restrict__ dstw = out + (size_t)(b * NCELLS + a * GG + ws0) * NC;

        #pragma unroll
        for (int it = 0; it < 2; ++it) {
            const int k = lane + 64 * it;       // one quad per k-row
            if (k < NC) {
                const f32x4 v = *reinterpret_cast<const f32x4*>(srcw + (size_t)k * GG);
                #pragma unroll
                for (int j = 0; j < 4; ++j)
                    ldsw[j * NC + k] = decode(v[j], k, ws0 + j, aw, ah);
            }
        }
        #pragma unroll
        for (int it = 0; it < 2; ++it) {
            const int e = lane + 64 * it;       // 4*85 = 340 floats = 85 float4
            if (e < NC) {
                const f32x4 v = *reinterpret_cast<const f32x4*>(ldsw + 4 * e);
                __builtin_nontemporal_store(v, reinterpret_cast<f32x4*>(dstw + 4 * e));
            }
        }
    }
}

extern "C" void kernel_launch(void* const* d_in, const int* in_sizes, int n_in,
                              void* d_out, int out_size, void* d_ws, size_t ws_size,
                              hipStream_t stream) {
    const float* x       = (const float*)d_in[0];
    const float* anchors = (const float*)d_in[1];
    float* out           = (float*)d_out;

    det_decode_kernel<<<dim3(NBLK), dim3(256), 0, stream>>>(x, anchors, out);
}